// Round 7
// baseline (615.679 us; speedup 1.0000x reference)
//
#include <hip/hip_runtime.h>
#include <math.h>

#define D_ 128
#define H_ 160
#define W_ 160
#define NVOX (D_*H_*W_)
#define HW (H_*W_)
#define N4 (NVOX/4)
#define HW4 (HW/4)

// Gaussian kernel, sigma=1, radius=2, normalized
#define K0 0.40261996f
#define K1 0.24420134f
#define K2 0.05448868f

union F4 { float4 v; float a[4]; };

__device__ __forceinline__ float4 zero4() { float4 z; z.x=z.y=z.z=z.w=0.f; return z; }
__device__ __forceinline__ float4 bcast4(float x) { float4 r; r.x=r.y=r.z=r.w=x; return r; }
__device__ __forceinline__ int imin(int a, int b) { return a < b ? a : b; }
__device__ __forceinline__ int imax(int a, int b) { return a > b ? a : b; }

__device__ __forceinline__ float fetch_mov(const float* __restrict__ m, int d, int h, int w) {
    if ((unsigned)d >= (unsigned)D_ || (unsigned)h >= (unsigned)H_ || (unsigned)w >= (unsigned)W_) return 0.0f;
    return m[(size_t)(d*H_ + h)*W_ + w];
}

__device__ __forceinline__ float trilerp(const float* __restrict__ mov,
                                         float cd, float ch, float cw) {
    float fd = floorf(cd), fh = floorf(ch), fw = floorf(cw);
    int di = (int)fd, hi = (int)fh, wi = (int)fw;
    float td = cd - fd, th = ch - fh, tw = cw - fw;
    float c000, c001, c010, c011, c100, c101, c110, c111;
    if (di >= 0 && di < D_-1 && hi >= 0 && hi < H_-1 && wi >= 0 && wi < W_-1) {
        const float* p = mov + (size_t)di*HW + hi*W_ + wi;
        c000 = p[0];    c001 = p[1];
        c010 = p[W_];   c011 = p[W_+1];
        const float* q = p + HW;
        c100 = q[0];    c101 = q[1];
        c110 = q[W_];   c111 = q[W_+1];
    } else {
        c000 = fetch_mov(mov, di,   hi,   wi  );
        c001 = fetch_mov(mov, di,   hi,   wi+1);
        c010 = fetch_mov(mov, di,   hi+1, wi  );
        c011 = fetch_mov(mov, di,   hi+1, wi+1);
        c100 = fetch_mov(mov, di+1, hi,   wi  );
        c101 = fetch_mov(mov, di+1, hi,   wi+1);
        c110 = fetch_mov(mov, di+1, hi+1, wi  );
        c111 = fetch_mov(mov, di+1, hi+1, wi+1);
    }
    float c00 = c000 + tw*(c001 - c000);
    float c01 = c010 + tw*(c011 - c010);
    float c10 = c100 + tw*(c101 - c100);
    float c11 = c110 + tw*(c111 - c110);
    float c0 = c00 + th*(c01 - c00);
    float c1 = c10 + th*(c11 - c10);
    return c0 + td*(c1 - c0);
}

// select arr[k] from the 8 floats {A.a[0..3], B.a[0..3]} via cndmask tree (k in [0,7])
__device__ __forceinline__ float sel8(const F4& A, const F4& B, int k) {
    float s0 = (k & 4) ? B.a[0] : A.a[0];
    float s1 = (k & 4) ? B.a[1] : A.a[1];
    float s2 = (k & 4) ? B.a[2] : A.a[2];
    float s3 = (k & 4) ? B.a[3] : A.a[3];
    float t0 = (k & 2) ? s2 : s0;
    float t1 = (k & 2) ? s3 : s1;
    return (k & 1) ? t1 : t0;
}

// ---------------------------------------------------------------------------
// v4 force_wh (UNCHANGED from the 582/567 µs runs): phase A restructured to
// starve the VMEM path.
//   A0: stage warped/fix center-plane tiles [38][48] in LDS, CLAMP-filled
//       (clamp-fill == the edge substitute rule).
//   A1: h/w taps from LDS; 7 unconditional coalesced global b128 loads
//       (d+-1 via clamped-plane offsets + 3 vf).
//   Phases B/C/D: swizzled u overlay (verified v3).
// ---------------------------------------------------------------------------
#define UROW 48   // 12 f4 per row (10 used + swizzle domain padding)

__global__ __launch_bounds__(256, 4) void force_wh_kernel(const float* __restrict__ warped,
                                                          const float* __restrict__ fix,
                                                          const float* __restrict__ vf,
                                                          float* __restrict__ tout,
                                                          int zero_vf) {
    __shared__ float u[3][36][UROW];  // phase A1 out; phase C/D: s1 overlay
    __shared__ float tw[38][48];      // warped[d] tile, rows h0-3..h0+34, cols w0-8..w0+39 (clamped)
    __shared__ float tf[38][48];      // fix[d] tile, same footprint
    const int tx = threadIdx.x;       // 0..7
    const int ty = threadIdx.y;       // 0..31
    const int tid = ty*8 + tx;
    const int bswz = (blockIdx.x & 7)*400 + (blockIdx.x >> 3);
    const int d   = bswz / 25;
    const int rem = bswz % 25;
    const int h0 = (rem / 5) * 32;
    const int w0 = (rem % 5) * 32;

    // swizzled f4 accessor: logical f4-col fc of row r lives at fc ^ (r&3)
    #define UF4(ch, r, fc) (((float4*)&u[(ch)][(r)][0]) + ((fc) ^ ((r)&3)))

    // ---- phase A0: stage warped/fix center-plane tiles, clamp-filled.
    for (int s = tid; s < 456; s += 256) {
        int R  = s / 12, C4 = s % 12;
        int gh = h0 - 3 + R;
        int ghc = gh < 0 ? 0 : (gh > H_-1 ? H_-1 : gh);
        int gw = w0 - 8 + 4*C4;
        size_t rb = (size_t)d*HW + (size_t)ghc*W_;
        float4 wv, fv;
        if (gw < 0) {
            wv = bcast4(warped[rb]);  fv = bcast4(fix[rb]);
        } else if (gw + 4 > W_) {
            wv = bcast4(warped[rb + W_-1]); fv = bcast4(fix[rb + W_-1]);
        } else {
            wv = *(const float4*)(warped + rb + gw);
            fv = *(const float4*)(fix    + rb + gw);
        }
        *(float4*)&tw[R][4*C4] = wv;
        *(float4*)&tf[R][4*C4] = fv;
    }
    __syncthreads();

    // ---- phase A1: demons force from LDS taps + 7 batched global loads.
    for (int slot = tid; slot < 360; slot += 256) {
        int r = slot/10, c = slot%10;
        int gh = h0 - 2 + r;
        int gw = w0 - 4 + 4*c;
        F4 o0, o1, o2;
        if ((unsigned)gh < (unsigned)H_ && gw >= 0 && gw + 4 <= W_) {
            size_t base = (size_t)d*HW + (size_t)gh*W_ + gw;
            int i4 = (int)(base >> 2);
            int up = (d < D_-1) ?  (HW/4) : 0;
            int dn = (d > 0)    ? -(HW/4) : 0;
            const float4* w4p = (const float4*)warped;
            const float4* f4p = (const float4*)fix;
            F4 du, dnv, fdu, fdn;
            du.v  = w4p[i4 + up];
            dnv.v = w4p[i4 + dn];
            fdu.v = f4p[i4 + up];
            fdn.v = f4p[i4 + dn];
            if (zero_vf) {
                o0.v = zero4(); o1.v = zero4(); o2.v = zero4();
            } else {
                o0.v = ((const float4*)vf)[i4];
                o1.v = ((const float4*)vf)[i4 + N4];
                o2.v = ((const float4*)vf)[i4 + 2*N4];
            }
            int sr = r + 1, sc = 4*c + 4;
            F4 cc, fc, hu, hd, fhu, fhd;
            cc.v  = *(const float4*)&tw[sr  ][sc];
            fc.v  = *(const float4*)&tf[sr  ][sc];
            hu.v  = *(const float4*)&tw[sr+1][sc];
            hd.v  = *(const float4*)&tw[sr-1][sc];
            fhu.v = *(const float4*)&tf[sr+1][sc];
            fhd.v = *(const float4*)&tf[sr-1][sc];
            float cl = tw[sr][sc-1], cr = tw[sr][sc+4];
            float fl = tf[sr][sc-1], fr = tf[sr][sc+4];
            float hs  = (gh==0 || gh==H_-1) ? 1.f : 0.5f;
            float dsc = (d==0  || d==D_-1)  ? 1.f : 0.5f;
            float m [6] = {cl, cc.a[0], cc.a[1], cc.a[2], cc.a[3], cr};
            float fm[6] = {fl, fc.a[0], fc.a[1], fc.a[2], fc.a[3], fr};
            #pragma unroll
            for (int j = 0; j < 4; ++j) {
                int wj = gw + j;
                float wsc  = (wj == 0 || wj == W_-1) ? 1.f : 0.5f;
                float prev  = (wj == 0)    ? m[1]  : m[j];
                float next  = (wj == W_-1) ? m[4]  : m[j+2];
                float fprev = (wj == 0)    ? fm[1] : fm[j];
                float fnext = (wj == W_-1) ? fm[4] : fm[j+2];
                float G0 = dsc*(du.a[j] - dnv.a[j]) + dsc*(fdu.a[j] - fdn.a[j]);
                float G1 = hs *(hu.a[j] - hd.a[j])  + hs *(fhu.a[j] - fhd.a[j]);
                float G2 = wsc*(next - prev)        + wsc*(fnext - fprev);
                float diff = cc.a[j] - fc.a[j];
                float denom = G0*G0 + G1*G1 + G2*G2 + diff*diff;
                float scale = (denom > 1e-6f) ? (-diff/denom) : 0.0f;
                o0.a[j] += scale*G0;
                o1.a[j] += scale*G1;
                o2.a[j] += scale*G2;
            }
        } else {
            o0.v = zero4(); o1.v = zero4(); o2.v = zero4();
        }
        *UF4(0, r, c) = o0.v;
        *UF4(1, r, c) = o1.v;
        *UF4(2, r, c) = o2.v;
    }
    __syncthreads();

    // ---- phase B: W-conv into registers. 216 jobs = 3ch x 36 rows x 2 halves.
    F4 wout[4];
    int jch = 0, jr = 0, jh = 0;
    const bool has = (tid < 216);
    if (has) {
        jch = tid / 72;
        int rem2 = tid % 72;
        jr = rem2 >> 1;
        jh = rem2 & 1;
        F4 q[6];
        #pragma unroll
        for (int i = 0; i < 6; ++i) q[i].v = *UF4(jch, jr, 4*jh + i);
        float mm[24];
        #pragma unroll
        for (int i = 0; i < 6; ++i) {
            mm[4*i+0]=q[i].a[0]; mm[4*i+1]=q[i].a[1]; mm[4*i+2]=q[i].a[2]; mm[4*i+3]=q[i].a[3];
        }
        #pragma unroll
        for (int o = 0; o < 16; ++o)
            wout[o>>2].a[o&3] = K2*(mm[o+2]+mm[o+6]) + K1*(mm[o+3]+mm[o+5]) + K0*mm[o+4];
    }
    __syncthreads();

    // ---- phase C: write s1 overlay back into u
    if (has) {
        #pragma unroll
        for (int f = 0; f < 4; ++f) *UF4(jch, jr, 4*jh + f) = wout[f].v;
    }
    __syncthreads();

    // ---- phase D: H-conv from overlay + store
    size_t base = (size_t)d*HW + (h0+ty)*W_ + w0 + 4*tx;
    #pragma unroll
    for (int ch = 0; ch < 3; ++ch) {
        F4 q0, q1, q2, q3, q4;
        q0.v = *UF4(ch, ty  , tx);
        q1.v = *UF4(ch, ty+1, tx);
        q2.v = *UF4(ch, ty+2, tx);
        q3.v = *UF4(ch, ty+3, tx);
        q4.v = *UF4(ch, ty+4, tx);
        float4 s2;
        s2.x = K2*(q0.a[0]+q4.a[0]) + K1*(q1.a[0]+q3.a[0]) + K0*q2.a[0];
        s2.y = K2*(q0.a[1]+q4.a[1]) + K1*(q1.a[1]+q3.a[1]) + K0*q2.a[1];
        s2.z = K2*(q0.a[2]+q4.a[2]) + K1*(q1.a[2]+q3.a[2]) + K0*q2.a[2];
        s2.w = K2*(q0.a[3]+q4.a[3]) + K1*(q1.a[3]+q3.a[3]) + K0*q2.a[3];
        *(float4*)(tout + (size_t)ch*NVOX + base) = s2;
    }
    #undef UF4
}

// ---------------------------------------------------------------------------
// v7 smooth_d_warp: v6 structure (LDS tap sharing, constant thread count) +
// j-shared window trilerp. The 4 outputs of a thread's f4 have near-identical
// displacements (vf Gaussian-smoothed), so their 32 corners almost always lie
// in 4 row-segments of <=8 consecutive floats. Fast path (per-lane): when
// di/hi uniform across j, interior in d/h, and the w-span fits an aligned
// 8-float window: 8 aligned b128 loads replace 32 scattered scalars (-75%
// scattered VMEM instrs, the ~15-20ns currency); corners extracted via
// 7-cndmask sel8 trees (VALU 25% busy -> headroom). Values bit-identical:
// extraction yields exact mov[...] floats, lerp chain order unchanged;
// w-edge cval=0 handled by zero-masks (window clamped to W-8). d/h-edge
// lanes and rare j-split lanes take the original slow path, exec-masked.
// ---------------------------------------------------------------------------
__global__ __launch_bounds__(256) void smooth_d_warp_kernel(const float* __restrict__ t,
                                                            const float* __restrict__ mov,
                                                            float* __restrict__ vf_out,
                                                            float* __restrict__ warped_out,
                                                            int do_warp) {
    __shared__ float4 sm[24][64];     // [ch*8 + r][hw4-lane], planes d0-2 .. d0+5
    const int chunk = (blockIdx.x & 7)*400 + (blockIdx.x >> 3);
    const int db = chunk / 100;       // d-tile: planes db*4 .. db*4+3
    const int hb = chunk % 100;       // hw-tile: f4 indices hb*64 .. hb*64+63
    const int tdx = threadIdx.x & 63; // hw4 lane
    const int tdz = threadIdx.x >> 6; // d lane 0..3
    const int d0 = db*4;
    const int hw4 = hb*64 + tdx;

    // ---- stage 8 planes x 3 ch: 24 plane-rows, wave w loads rows w*6..w*6+5
    #pragma unroll
    for (int i = 0; i < 6; ++i) {
        int pc = tdz*6 + i;           // 0..23
        int ch = pc >> 3;             // pc/8
        int r  = pc & 7;              // plane row
        int p  = d0 - 2 + r;
        const float4* tp = (const float4*)(t + (size_t)ch*NVOX);
        sm[pc][tdx] = ((unsigned)p < (unsigned)D_) ? tp[p*HW4 + hw4] : zero4();
    }
    __syncthreads();

    // ---- D-conv from LDS + warp. Output (d0+tdz, hw4): taps rows tdz..tdz+4.
    const int d = d0 + tdz;
    const int w = (hw4 % (W_/4)) * 4;
    const int h = hw4 / (W_/4);
    F4 va[3];
    #pragma unroll
    for (int ch = 0; ch < 3; ++ch) {
        F4 q0, q1, q2, q3, q4;
        q0.v = sm[ch*8 + tdz    ][tdx];
        q1.v = sm[ch*8 + tdz + 1][tdx];
        q2.v = sm[ch*8 + tdz + 2][tdx];
        q3.v = sm[ch*8 + tdz + 3][tdx];
        q4.v = sm[ch*8 + tdz + 4][tdx];
        va[ch].a[0] = K2*(q0.a[0]+q4.a[0]) + K1*(q1.a[0]+q3.a[0]) + K0*q2.a[0];
        va[ch].a[1] = K2*(q0.a[1]+q4.a[1]) + K1*(q1.a[1]+q3.a[1]) + K0*q2.a[1];
        va[ch].a[2] = K2*(q0.a[2]+q4.a[2]) + K1*(q1.a[2]+q3.a[2]) + K0*q2.a[2];
        va[ch].a[3] = K2*(q0.a[3]+q4.a[3]) + K1*(q1.a[3]+q3.a[3]) + K0*q2.a[3];
    }
    const int i4 = d*HW4 + hw4;
    ((float4*)vf_out)[i4]        = va[0].v;
    ((float4*)vf_out)[i4 + N4]   = va[1].v;
    ((float4*)vf_out)[i4 + 2*N4] = va[2].v;
    if (do_warp) {
        int di[4], hi[4], wi[4];
        float td[4], th[4], twf[4];
        #pragma unroll
        for (int j = 0; j < 4; ++j) {
            float cd  = (float)d       + va[0].a[j];
            float ch2 = (float)h       + va[1].a[j];
            float cw  = (float)(w + j) + va[2].a[j];
            float fd = floorf(cd), fh = floorf(ch2), fw = floorf(cw);
            di[j] = (int)fd; hi[j] = (int)fh; wi[j] = (int)fw;
            td[j] = cd - fd; th[j] = ch2 - fh; twf[j] = cw - fw;
        }
        bool uni = (di[0]==di[1]) & (di[0]==di[2]) & (di[0]==di[3])
                 & (hi[0]==hi[1]) & (hi[0]==hi[2]) & (hi[0]==hi[3]);
        bool inter = (di[0] >= 0) & (di[0] <= D_-2) & (hi[0] >= 0) & (hi[0] <= H_-2);
        int wmin = imin(imin(wi[0], wi[1]), imin(wi[2], wi[3]));
        int e = imin(imax(wmin, 0) & ~3, W_-8);
        bool okw = true;
        #pragma unroll
        for (int j = 0; j < 4; ++j) {
            int k = wi[j] - e;
            okw &= ((k >= 0 && k <= 6) || (k == -1 && wi[j] == -1) || (k == 7 && e == W_-8));
        }
        F4 r4o;
        if (uni & inter & okw) {
            const float* r00 = mov + (size_t)di[0]*HW + (size_t)hi[0]*W_ + e;
            F4 A00,B00,A01,B01,A10,B10,A11,B11;
            A00.v = *(const float4*)(r00);         B00.v = *(const float4*)(r00+4);
            A01.v = *(const float4*)(r00+W_);      B01.v = *(const float4*)(r00+W_+4);
            A10.v = *(const float4*)(r00+HW);      B10.v = *(const float4*)(r00+HW+4);
            A11.v = *(const float4*)(r00+HW+W_);   B11.v = *(const float4*)(r00+HW+W_+4);
            #pragma unroll
            for (int j = 0; j < 4; ++j) {
                int k = wi[j] - e;
                bool z0 = (wi[j] < 0);        // corner w = -1   -> cval 0
                bool z1 = (wi[j] >= W_-1);    // corner w = W    -> cval 0
                float c000 = z0 ? 0.f : sel8(A00, B00, k);
                float c001 = z1 ? 0.f : sel8(A00, B00, k+1);
                float c010 = z0 ? 0.f : sel8(A01, B01, k);
                float c011 = z1 ? 0.f : sel8(A01, B01, k+1);
                float c100 = z0 ? 0.f : sel8(A10, B10, k);
                float c101 = z1 ? 0.f : sel8(A10, B10, k+1);
                float c110 = z0 ? 0.f : sel8(A11, B11, k);
                float c111 = z1 ? 0.f : sel8(A11, B11, k+1);
                float c00 = c000 + twf[j]*(c001 - c000);
                float c01 = c010 + twf[j]*(c011 - c010);
                float c10 = c100 + twf[j]*(c101 - c100);
                float c11 = c110 + twf[j]*(c111 - c110);
                float c0 = c00 + th[j]*(c01 - c00);
                float c1 = c10 + th[j]*(c11 - c10);
                r4o.a[j] = c0 + td[j]*(c1 - c0);
            }
        } else {
            #pragma unroll
            for (int j = 0; j < 4; ++j) {
                float cd  = (float)d       + va[0].a[j];
                float ch2 = (float)h       + va[1].a[j];
                float cw  = (float)(w + j) + va[2].a[j];
                r4o.a[j] = trilerp(mov, cd, ch2, cw);
            }
        }
        ((float4*)warped_out)[i4] = r4o.v;
    }
}

extern "C" void kernel_launch(void* const* d_in, const int* in_sizes, int n_in,
                              void* d_out, int out_size, void* d_ws, size_t ws_size,
                              hipStream_t stream) {
    const float* mov = (const float*)d_in[0];
    const float* fix = (const float*)d_in[1];
    const int ITERS = 10;

    float* ws     = (float*)d_ws;
    float* vfA    = ws;                       // 3N — the vf state
    float* tbuf   = ws + (size_t)3*NVOX;      // 3N — WH-smoothed field
    float* warped = ws + (size_t)6*NVOX;      // N

    for (int it = 0; it < ITERS; ++it) {
        // it==0: vf == 0 => warped == mov exactly (integer-coordinate trilerp)
        const float* wsrc = (it == 0) ? mov : warped;
        force_wh_kernel<<<dim3(3200), dim3(8,32), 0, stream>>>(wsrc, fix, vfA, tbuf,
                                                               it == 0 ? 1 : 0);
        float* vdst = (it == ITERS-1) ? (float*)d_out : vfA;
        smooth_d_warp_kernel<<<dim3(3200), dim3(256), 0, stream>>>(tbuf, mov, vdst, warped,
                                                                   it == ITERS-1 ? 0 : 1);
    }
}

// Round 8
// 554.685 us; speedup vs baseline: 1.1100x; 1.1100x over previous
//
#include <hip/hip_runtime.h>
#include <math.h>

#define D_ 128
#define H_ 160
#define W_ 160
#define NVOX (D_*H_*W_)
#define HW (H_*W_)
#define N4 (NVOX/4)
#define HW4 (HW/4)

// Gaussian kernel, sigma=1, radius=2, normalized
#define K0 0.40261996f
#define K1 0.24420134f
#define K2 0.05448868f

union F4 { float4 v; float a[4]; };

__device__ __forceinline__ float4 zero4() { float4 z; z.x=z.y=z.z=z.w=0.f; return z; }
__device__ __forceinline__ float4 bcast4(float x) { float4 r; r.x=r.y=r.z=r.w=x; return r; }

// async global->LDS, 16B per lane. HW semantics: LDS dest = wave-uniform base
// + lane*16 (our &dst[lane] matches exactly); global src is per-lane.
#define GLOAD_LDS16(g, l) __builtin_amdgcn_global_load_lds( \
    (const __attribute__((address_space(1))) void*)(g), \
    (__attribute__((address_space(3))) void*)(l), 16, 0, 0)

__device__ __forceinline__ float fetch_mov(const float* __restrict__ m, int d, int h, int w) {
    if ((unsigned)d >= (unsigned)D_ || (unsigned)h >= (unsigned)H_ || (unsigned)w >= (unsigned)W_) return 0.0f;
    return m[(size_t)(d*H_ + h)*W_ + w];
}

__device__ __forceinline__ float trilerp(const float* __restrict__ mov,
                                         float cd, float ch, float cw) {
    float fd = floorf(cd), fh = floorf(ch), fw = floorf(cw);
    int di = (int)fd, hi = (int)fh, wi = (int)fw;
    float td = cd - fd, th = ch - fh, tw = cw - fw;
    float c000, c001, c010, c011, c100, c101, c110, c111;
    if (di >= 0 && di < D_-1 && hi >= 0 && hi < H_-1 && wi >= 0 && wi < W_-1) {
        const float* p = mov + (size_t)di*HW + hi*W_ + wi;
        c000 = p[0];    c001 = p[1];
        c010 = p[W_];   c011 = p[W_+1];
        const float* q = p + HW;
        c100 = q[0];    c101 = q[1];
        c110 = q[W_];   c111 = q[W_+1];
    } else {
        c000 = fetch_mov(mov, di,   hi,   wi  );
        c001 = fetch_mov(mov, di,   hi,   wi+1);
        c010 = fetch_mov(mov, di,   hi+1, wi  );
        c011 = fetch_mov(mov, di,   hi+1, wi+1);
        c100 = fetch_mov(mov, di+1, hi,   wi  );
        c101 = fetch_mov(mov, di+1, hi,   wi+1);
        c110 = fetch_mov(mov, di+1, hi+1, wi  );
        c111 = fetch_mov(mov, di+1, hi+1, wi+1);
    }
    float c00 = c000 + tw*(c001 - c000);
    float c01 = c010 + tw*(c011 - c010);
    float c10 = c100 + tw*(c101 - c100);
    float c11 = c110 + tw*(c111 - c110);
    float c0 = c00 + th*(c01 - c00);
    float c1 = c10 + th*(c11 - c10);
    return c0 + td*(c1 - c0);
}

// ---------------------------------------------------------------------------
// v4 force_wh (UNCHANGED from the 582/567 µs runs): phase A restructured to
// starve the VMEM path.
//   A0: stage warped/fix center-plane tiles [38][48] in LDS, CLAMP-filled
//       (clamp-fill == the edge substitute rule).
//   A1: h/w taps from LDS; 7 unconditional coalesced global b128 loads
//       (d+-1 via clamped-plane offsets + 3 vf).
//   Phases B/C/D: swizzled u overlay (verified v3).
// ---------------------------------------------------------------------------
#define UROW 48   // 12 f4 per row (10 used + swizzle domain padding)

__global__ __launch_bounds__(256, 4) void force_wh_kernel(const float* __restrict__ warped,
                                                          const float* __restrict__ fix,
                                                          const float* __restrict__ vf,
                                                          float* __restrict__ tout,
                                                          int zero_vf) {
    __shared__ float u[3][36][UROW];  // phase A1 out; phase C/D: s1 overlay
    __shared__ float tw[38][48];      // warped[d] tile, rows h0-3..h0+34, cols w0-8..w0+39 (clamped)
    __shared__ float tf[38][48];      // fix[d] tile, same footprint
    const int tx = threadIdx.x;       // 0..7
    const int ty = threadIdx.y;       // 0..31
    const int tid = ty*8 + tx;
    const int bswz = (blockIdx.x & 7)*400 + (blockIdx.x >> 3);
    const int d   = bswz / 25;
    const int rem = bswz % 25;
    const int h0 = (rem / 5) * 32;
    const int w0 = (rem % 5) * 32;

    // swizzled f4 accessor: logical f4-col fc of row r lives at fc ^ (r&3)
    #define UF4(ch, r, fc) (((float4*)&u[(ch)][(r)][0]) + ((fc) ^ ((r)&3)))

    // ---- phase A0: stage warped/fix center-plane tiles, clamp-filled.
    for (int s = tid; s < 456; s += 256) {
        int R  = s / 12, C4 = s % 12;
        int gh = h0 - 3 + R;
        int ghc = gh < 0 ? 0 : (gh > H_-1 ? H_-1 : gh);
        int gw = w0 - 8 + 4*C4;
        size_t rb = (size_t)d*HW + (size_t)ghc*W_;
        float4 wv, fv;
        if (gw < 0) {
            wv = bcast4(warped[rb]);  fv = bcast4(fix[rb]);
        } else if (gw + 4 > W_) {
            wv = bcast4(warped[rb + W_-1]); fv = bcast4(fix[rb + W_-1]);
        } else {
            wv = *(const float4*)(warped + rb + gw);
            fv = *(const float4*)(fix    + rb + gw);
        }
        *(float4*)&tw[R][4*C4] = wv;
        *(float4*)&tf[R][4*C4] = fv;
    }
    __syncthreads();

    // ---- phase A1: demons force from LDS taps + 7 batched global loads.
    for (int slot = tid; slot < 360; slot += 256) {
        int r = slot/10, c = slot%10;
        int gh = h0 - 2 + r;
        int gw = w0 - 4 + 4*c;
        F4 o0, o1, o2;
        if ((unsigned)gh < (unsigned)H_ && gw >= 0 && gw + 4 <= W_) {
            size_t base = (size_t)d*HW + (size_t)gh*W_ + gw;
            int i4 = (int)(base >> 2);
            int up = (d < D_-1) ?  (HW/4) : 0;
            int dn = (d > 0)    ? -(HW/4) : 0;
            const float4* w4p = (const float4*)warped;
            const float4* f4p = (const float4*)fix;
            F4 du, dnv, fdu, fdn;
            du.v  = w4p[i4 + up];
            dnv.v = w4p[i4 + dn];
            fdu.v = f4p[i4 + up];
            fdn.v = f4p[i4 + dn];
            if (zero_vf) {
                o0.v = zero4(); o1.v = zero4(); o2.v = zero4();
            } else {
                o0.v = ((const float4*)vf)[i4];
                o1.v = ((const float4*)vf)[i4 + N4];
                o2.v = ((const float4*)vf)[i4 + 2*N4];
            }
            int sr = r + 1, sc = 4*c + 4;
            F4 cc, fc, hu, hd, fhu, fhd;
            cc.v  = *(const float4*)&tw[sr  ][sc];
            fc.v  = *(const float4*)&tf[sr  ][sc];
            hu.v  = *(const float4*)&tw[sr+1][sc];
            hd.v  = *(const float4*)&tw[sr-1][sc];
            fhu.v = *(const float4*)&tf[sr+1][sc];
            fhd.v = *(const float4*)&tf[sr-1][sc];
            float cl = tw[sr][sc-1], cr = tw[sr][sc+4];
            float fl = tf[sr][sc-1], fr = tf[sr][sc+4];
            float hs  = (gh==0 || gh==H_-1) ? 1.f : 0.5f;
            float dsc = (d==0  || d==D_-1)  ? 1.f : 0.5f;
            float m [6] = {cl, cc.a[0], cc.a[1], cc.a[2], cc.a[3], cr};
            float fm[6] = {fl, fc.a[0], fc.a[1], fc.a[2], fc.a[3], fr};
            #pragma unroll
            for (int j = 0; j < 4; ++j) {
                int wj = gw + j;
                float wsc  = (wj == 0 || wj == W_-1) ? 1.f : 0.5f;
                float prev  = (wj == 0)    ? m[1]  : m[j];
                float next  = (wj == W_-1) ? m[4]  : m[j+2];
                float fprev = (wj == 0)    ? fm[1] : fm[j];
                float fnext = (wj == W_-1) ? fm[4] : fm[j+2];
                float G0 = dsc*(du.a[j] - dnv.a[j]) + dsc*(fdu.a[j] - fdn.a[j]);
                float G1 = hs *(hu.a[j] - hd.a[j])  + hs *(fhu.a[j] - fhd.a[j]);
                float G2 = wsc*(next - prev)        + wsc*(fnext - fprev);
                float diff = cc.a[j] - fc.a[j];
                float denom = G0*G0 + G1*G1 + G2*G2 + diff*diff;
                float scale = (denom > 1e-6f) ? (-diff/denom) : 0.0f;
                o0.a[j] += scale*G0;
                o1.a[j] += scale*G1;
                o2.a[j] += scale*G2;
            }
        } else {
            o0.v = zero4(); o1.v = zero4(); o2.v = zero4();
        }
        *UF4(0, r, c) = o0.v;
        *UF4(1, r, c) = o1.v;
        *UF4(2, r, c) = o2.v;
    }
    __syncthreads();

    // ---- phase B: W-conv into registers. 216 jobs = 3ch x 36 rows x 2 halves.
    F4 wout[4];
    int jch = 0, jr = 0, jh = 0;
    const bool has = (tid < 216);
    if (has) {
        jch = tid / 72;
        int rem2 = tid % 72;
        jr = rem2 >> 1;
        jh = rem2 & 1;
        F4 q[6];
        #pragma unroll
        for (int i = 0; i < 6; ++i) q[i].v = *UF4(jch, jr, 4*jh + i);
        float mm[24];
        #pragma unroll
        for (int i = 0; i < 6; ++i) {
            mm[4*i+0]=q[i].a[0]; mm[4*i+1]=q[i].a[1]; mm[4*i+2]=q[i].a[2]; mm[4*i+3]=q[i].a[3];
        }
        #pragma unroll
        for (int o = 0; o < 16; ++o)
            wout[o>>2].a[o&3] = K2*(mm[o+2]+mm[o+6]) + K1*(mm[o+3]+mm[o+5]) + K0*mm[o+4];
    }
    __syncthreads();

    // ---- phase C: write s1 overlay back into u
    if (has) {
        #pragma unroll
        for (int f = 0; f < 4; ++f) *UF4(jch, jr, 4*jh + f) = wout[f].v;
    }
    __syncthreads();

    // ---- phase D: H-conv from overlay + store
    size_t base = (size_t)d*HW + (h0+ty)*W_ + w0 + 4*tx;
    #pragma unroll
    for (int ch = 0; ch < 3; ++ch) {
        F4 q0, q1, q2, q3, q4;
        q0.v = *UF4(ch, ty  , tx);
        q1.v = *UF4(ch, ty+1, tx);
        q2.v = *UF4(ch, ty+2, tx);
        q3.v = *UF4(ch, ty+3, tx);
        q4.v = *UF4(ch, ty+4, tx);
        float4 s2;
        s2.x = K2*(q0.a[0]+q4.a[0]) + K1*(q1.a[0]+q3.a[0]) + K0*q2.a[0];
        s2.y = K2*(q0.a[1]+q4.a[1]) + K1*(q1.a[1]+q3.a[1]) + K0*q2.a[1];
        s2.z = K2*(q0.a[2]+q4.a[2]) + K1*(q1.a[2]+q3.a[2]) + K0*q2.a[2];
        s2.w = K2*(q0.a[3]+q4.a[3]) + K1*(q1.a[3]+q3.a[3]) + K0*q2.a[3];
        *(float4*)(tout + (size_t)ch*NVOX + base) = s2;
    }
    #undef UF4
}

// ---------------------------------------------------------------------------
// v8 smooth_d_warp: v6 structure (best measured: 567 µs total) with staging
// via async global_load_lds width=16 (direct HBM->LDS DMA, no VGPR round
// trip, no s_waitcnt until the barrier). v7's window-trilerp reverted: it
// proved the gather is line-request/latency-bound, not instruction-bound —
// lean scalar trilerp + max TLP is optimal.
// Each wave (tdz) stages rows tdz*6..tdz*6+5 of sm: LDS dest = wave-uniform
// row base + lane*16 (the exact gload_lds HW pattern); global src per-lane.
// Out-of-range planes: wave-uniform plain zero-store branch (d-edge tiles
// only) == the D-conv's zero padding.
// ---------------------------------------------------------------------------
__global__ __launch_bounds__(256) void smooth_d_warp_kernel(const float* __restrict__ t,
                                                            const float* __restrict__ mov,
                                                            float* __restrict__ vf_out,
                                                            float* __restrict__ warped_out,
                                                            int do_warp) {
    __shared__ float4 sm[24][64];     // [ch*8 + r][hw4-lane], planes d0-2 .. d0+5
    const int chunk = (blockIdx.x & 7)*400 + (blockIdx.x >> 3);
    const int db = chunk / 100;       // d-tile: planes db*4 .. db*4+3
    const int hb = chunk % 100;       // hw-tile: f4 indices hb*64 .. hb*64+63
    const int tdx = threadIdx.x & 63; // hw4 lane
    const int tdz = threadIdx.x >> 6; // d lane 0..3 (== wave id)
    const int d0 = db*4;
    const int hw4 = hb*64 + tdx;

    // ---- stage 8 planes x 3 ch: 24 plane-rows, wave w stages rows w*6..w*6+5
    #pragma unroll
    for (int i = 0; i < 6; ++i) {
        int pc = tdz*6 + i;           // 0..23
        int ch = pc >> 3;             // pc/8
        int r  = pc & 7;              // plane row
        int p  = d0 - 2 + r;
        if ((unsigned)p < (unsigned)D_) {   // wave-uniform branch
            const float4* src = (const float4*)(t + (size_t)ch*NVOX) + (p*HW4 + hw4);
            GLOAD_LDS16(src, &sm[pc][tdx]);
        } else {
            sm[pc][tdx] = zero4();
        }
    }
    __syncthreads();

    // ---- D-conv from LDS + warp. Output (d0+tdz, hw4): taps rows tdz..tdz+4.
    const int d = d0 + tdz;
    const int w = (hw4 % (W_/4)) * 4;
    const int h = hw4 / (W_/4);
    F4 va[3];
    #pragma unroll
    for (int ch = 0; ch < 3; ++ch) {
        F4 q0, q1, q2, q3, q4;
        q0.v = sm[ch*8 + tdz    ][tdx];
        q1.v = sm[ch*8 + tdz + 1][tdx];
        q2.v = sm[ch*8 + tdz + 2][tdx];
        q3.v = sm[ch*8 + tdz + 3][tdx];
        q4.v = sm[ch*8 + tdz + 4][tdx];
        va[ch].a[0] = K2*(q0.a[0]+q4.a[0]) + K1*(q1.a[0]+q3.a[0]) + K0*q2.a[0];
        va[ch].a[1] = K2*(q0.a[1]+q4.a[1]) + K1*(q1.a[1]+q3.a[1]) + K0*q2.a[1];
        va[ch].a[2] = K2*(q0.a[2]+q4.a[2]) + K1*(q1.a[2]+q3.a[2]) + K0*q2.a[2];
        va[ch].a[3] = K2*(q0.a[3]+q4.a[3]) + K1*(q1.a[3]+q3.a[3]) + K0*q2.a[3];
    }
    const int i4 = d*HW4 + hw4;
    ((float4*)vf_out)[i4]        = va[0].v;
    ((float4*)vf_out)[i4 + N4]   = va[1].v;
    ((float4*)vf_out)[i4 + 2*N4] = va[2].v;
    if (do_warp) {
        F4 r4o;
        #pragma unroll
        for (int j = 0; j < 4; ++j) {
            float cd  = (float)d       + va[0].a[j];
            float ch2 = (float)h       + va[1].a[j];
            float cw  = (float)(w + j) + va[2].a[j];
            r4o.a[j] = trilerp(mov, cd, ch2, cw);
        }
        ((float4*)warped_out)[i4] = r4o.v;
    }
}

extern "C" void kernel_launch(void* const* d_in, const int* in_sizes, int n_in,
                              void* d_out, int out_size, void* d_ws, size_t ws_size,
                              hipStream_t stream) {
    const float* mov = (const float*)d_in[0];
    const float* fix = (const float*)d_in[1];
    const int ITERS = 10;

    float* ws     = (float*)d_ws;
    float* vfA    = ws;                       // 3N — the vf state
    float* tbuf   = ws + (size_t)3*NVOX;      // 3N — WH-smoothed field
    float* warped = ws + (size_t)6*NVOX;      // N

    for (int it = 0; it < ITERS; ++it) {
        // it==0: vf == 0 => warped == mov exactly (integer-coordinate trilerp)
        const float* wsrc = (it == 0) ? mov : warped;
        force_wh_kernel<<<dim3(3200), dim3(8,32), 0, stream>>>(wsrc, fix, vfA, tbuf,
                                                               it == 0 ? 1 : 0);
        float* vdst = (it == ITERS-1) ? (float*)d_out : vfA;
        smooth_d_warp_kernel<<<dim3(3200), dim3(256), 0, stream>>>(tbuf, mov, vdst, warped,
                                                                   it == ITERS-1 ? 0 : 1);
    }
}

// Round 9
// 538.475 us; speedup vs baseline: 1.1434x; 1.0301x over previous
//
#include <hip/hip_runtime.h>
#include <math.h>

#define D_ 128
#define H_ 160
#define W_ 160
#define NVOX (D_*H_*W_)
#define HW (H_*W_)
#define N4 (NVOX/4)
#define HW4 (HW/4)

// Gaussian kernel, sigma=1, radius=2, normalized
#define K0 0.40261996f
#define K1 0.24420134f
#define K2 0.05448868f

union F4 { float4 v; float a[4]; };

__device__ __forceinline__ float4 zero4() { float4 z; z.x=z.y=z.z=z.w=0.f; return z; }
__device__ __forceinline__ float4 bcast4(float x) { float4 r; r.x=r.y=r.z=r.w=x; return r; }

// async global->LDS, 16B per lane. HW semantics: LDS dest = wave-uniform base
// + lane*16 (our base+lane patterns match exactly); global src is per-lane.
#define GLOAD_LDS16(g, l) __builtin_amdgcn_global_load_lds( \
    (const __attribute__((address_space(1))) void*)(g), \
    (__attribute__((address_space(3))) void*)(l), 16, 0, 0)

__device__ __forceinline__ float fetch_mov(const float* __restrict__ m, int d, int h, int w) {
    if ((unsigned)d >= (unsigned)D_ || (unsigned)h >= (unsigned)H_ || (unsigned)w >= (unsigned)W_) return 0.0f;
    return m[(size_t)(d*H_ + h)*W_ + w];
}

__device__ __forceinline__ float trilerp(const float* __restrict__ mov,
                                         float cd, float ch, float cw) {
    float fd = floorf(cd), fh = floorf(ch), fw = floorf(cw);
    int di = (int)fd, hi = (int)fh, wi = (int)fw;
    float td = cd - fd, th = ch - fh, tw = cw - fw;
    float c000, c001, c010, c011, c100, c101, c110, c111;
    if (di >= 0 && di < D_-1 && hi >= 0 && hi < H_-1 && wi >= 0 && wi < W_-1) {
        const float* p = mov + (size_t)di*HW + hi*W_ + wi;
        c000 = p[0];    c001 = p[1];
        c010 = p[W_];   c011 = p[W_+1];
        const float* q = p + HW;
        c100 = q[0];    c101 = q[1];
        c110 = q[W_];   c111 = q[W_+1];
    } else {
        c000 = fetch_mov(mov, di,   hi,   wi  );
        c001 = fetch_mov(mov, di,   hi,   wi+1);
        c010 = fetch_mov(mov, di,   hi+1, wi  );
        c011 = fetch_mov(mov, di,   hi+1, wi+1);
        c100 = fetch_mov(mov, di+1, hi,   wi  );
        c101 = fetch_mov(mov, di+1, hi,   wi+1);
        c110 = fetch_mov(mov, di+1, hi+1, wi  );
        c111 = fetch_mov(mov, di+1, hi+1, wi+1);
    }
    float c00 = c000 + tw*(c001 - c000);
    float c01 = c010 + tw*(c011 - c010);
    float c10 = c100 + tw*(c101 - c100);
    float c11 = c110 + tw*(c111 - c110);
    float c0 = c00 + th*(c01 - c00);
    float c1 = c10 + th*(c11 - c10);
    return c0 + td*(c1 - c0);
}

// ---------------------------------------------------------------------------
// v9 force_wh: v4 structure with phase A0 converted to async global_load_lds
// (the v8-proven pattern). Per-lane src handles the h-clamp (clamped row
// address); w-edge f4-cols load a clamped in-bounds source and are patched
// post-barrier with the bcast edge value (only w0 in {0,128} tiles branch;
// wave-uniform). Two full-256 passes (s=tid, s=200+tid) keep every
// gload_lds wave at full exec; the 56-slot overlap double-loads identical
// bytes (benign). A1/B/C/D byte-identical to v4 (582/567/555 µs runs).
// ---------------------------------------------------------------------------
#define UROW 48   // 12 f4 per row (10 used + swizzle domain padding)

__global__ __launch_bounds__(256, 4) void force_wh_kernel(const float* __restrict__ warped,
                                                          const float* __restrict__ fix,
                                                          const float* __restrict__ vf,
                                                          float* __restrict__ tout,
                                                          int zero_vf) {
    __shared__ float u[3][36][UROW];  // phase A1 out; phase C/D: s1 overlay
    __shared__ float tw[38][48];      // warped[d] tile, rows h0-3..h0+34, cols w0-8..w0+39 (clamped)
    __shared__ float tf[38][48];      // fix[d] tile, same footprint
    const int tx = threadIdx.x;       // 0..7
    const int ty = threadIdx.y;       // 0..31
    const int tid = ty*8 + tx;
    const int bswz = (blockIdx.x & 7)*400 + (blockIdx.x >> 3);
    const int d   = bswz / 25;
    const int rem = bswz % 25;
    const int h0 = (rem / 5) * 32;
    const int w0 = (rem % 5) * 32;

    // swizzled f4 accessor: logical f4-col fc of row r lives at fc ^ (r&3)
    #define UF4(ch, r, fc) (((float4*)&u[(ch)][(r)][0]) + ((fc) ^ ((r)&3)))

    // ---- phase A0: stage warped/fix center-plane tiles via gload_lds.
    {
        const float* wplane = warped + (size_t)d*HW;
        const float* fplane = fix    + (size_t)d*HW;
        #pragma unroll
        for (int k = 0; k < 2; ++k) {
            int s = (k == 0) ? tid : 200 + tid;   // 0..255, 200..455: full waves
            int R  = s / 12, C4 = s % 12;
            int gh = h0 - 3 + R;
            int ghc = gh < 0 ? 0 : (gh > H_-1 ? H_-1 : gh);
            int gw = w0 - 8 + 4*C4;
            int gwc = gw < 0 ? 0 : (gw > W_-4 ? W_-4 : gw);
            const float* ws2 = wplane + (size_t)ghc*W_ + gwc;
            const float* fs2 = fplane + (size_t)ghc*W_ + gwc;
            GLOAD_LDS16(ws2, ((float4*)tw) + s);
            GLOAD_LDS16(fs2, ((float4*)tf) + s);
        }
    }
    __syncthreads();
    if (w0 == 0 || w0 == 128) {       // wave-uniform: patch w-edge f4-cols with bcast edge value
        if (tid < 152) {
            int vol = tid / 76;       // 0 = tw, 1 = tf
            int t2  = tid % 76;
            int R = t2 / 2, C = t2 % 2;
            float (*tp)[48] = vol ? tf : tw;
            int dstc = (w0 == 0) ? C : (10 + C);     // f4-cols {0,1} or {10,11}
            int srcf = (w0 == 0) ? 8 : 39;           // float at gw=0 / gw=W-1
            float v = tp[R][srcf];
            *(float4*)&tp[R][4*dstc] = bcast4(v);
        }
        __syncthreads();
    }

    // ---- phase A1: demons force from LDS taps + 7 batched global loads.
    for (int slot = tid; slot < 360; slot += 256) {
        int r = slot/10, c = slot%10;
        int gh = h0 - 2 + r;
        int gw = w0 - 4 + 4*c;
        F4 o0, o1, o2;
        if ((unsigned)gh < (unsigned)H_ && gw >= 0 && gw + 4 <= W_) {
            size_t base = (size_t)d*HW + (size_t)gh*W_ + gw;
            int i4 = (int)(base >> 2);
            int up = (d < D_-1) ?  (HW/4) : 0;
            int dn = (d > 0)    ? -(HW/4) : 0;
            const float4* w4p = (const float4*)warped;
            const float4* f4p = (const float4*)fix;
            F4 du, dnv, fdu, fdn;
            du.v  = w4p[i4 + up];
            dnv.v = w4p[i4 + dn];
            fdu.v = f4p[i4 + up];
            fdn.v = f4p[i4 + dn];
            if (zero_vf) {
                o0.v = zero4(); o1.v = zero4(); o2.v = zero4();
            } else {
                o0.v = ((const float4*)vf)[i4];
                o1.v = ((const float4*)vf)[i4 + N4];
                o2.v = ((const float4*)vf)[i4 + 2*N4];
            }
            int sr = r + 1, sc = 4*c + 4;
            F4 cc, fc, hu, hd, fhu, fhd;
            cc.v  = *(const float4*)&tw[sr  ][sc];
            fc.v  = *(const float4*)&tf[sr  ][sc];
            hu.v  = *(const float4*)&tw[sr+1][sc];
            hd.v  = *(const float4*)&tw[sr-1][sc];
            fhu.v = *(const float4*)&tf[sr+1][sc];
            fhd.v = *(const float4*)&tf[sr-1][sc];
            float cl = tw[sr][sc-1], cr = tw[sr][sc+4];
            float fl = tf[sr][sc-1], fr = tf[sr][sc+4];
            float hs  = (gh==0 || gh==H_-1) ? 1.f : 0.5f;
            float dsc = (d==0  || d==D_-1)  ? 1.f : 0.5f;
            float m [6] = {cl, cc.a[0], cc.a[1], cc.a[2], cc.a[3], cr};
            float fm[6] = {fl, fc.a[0], fc.a[1], fc.a[2], fc.a[3], fr};
            #pragma unroll
            for (int j = 0; j < 4; ++j) {
                int wj = gw + j;
                float wsc  = (wj == 0 || wj == W_-1) ? 1.f : 0.5f;
                float prev  = (wj == 0)    ? m[1]  : m[j];
                float next  = (wj == W_-1) ? m[4]  : m[j+2];
                float fprev = (wj == 0)    ? fm[1] : fm[j];
                float fnext = (wj == W_-1) ? fm[4] : fm[j+2];
                float G0 = dsc*(du.a[j] - dnv.a[j]) + dsc*(fdu.a[j] - fdn.a[j]);
                float G1 = hs *(hu.a[j] - hd.a[j])  + hs *(fhu.a[j] - fhd.a[j]);
                float G2 = wsc*(next - prev)        + wsc*(fnext - fprev);
                float diff = cc.a[j] - fc.a[j];
                float denom = G0*G0 + G1*G1 + G2*G2 + diff*diff;
                float scale = (denom > 1e-6f) ? (-diff/denom) : 0.0f;
                o0.a[j] += scale*G0;
                o1.a[j] += scale*G1;
                o2.a[j] += scale*G2;
            }
        } else {
            o0.v = zero4(); o1.v = zero4(); o2.v = zero4();
        }
        *UF4(0, r, c) = o0.v;
        *UF4(1, r, c) = o1.v;
        *UF4(2, r, c) = o2.v;
    }
    __syncthreads();

    // ---- phase B: W-conv into registers. 216 jobs = 3ch x 36 rows x 2 halves.
    F4 wout[4];
    int jch = 0, jr = 0, jh = 0;
    const bool has = (tid < 216);
    if (has) {
        jch = tid / 72;
        int rem2 = tid % 72;
        jr = rem2 >> 1;
        jh = rem2 & 1;
        F4 q[6];
        #pragma unroll
        for (int i = 0; i < 6; ++i) q[i].v = *UF4(jch, jr, 4*jh + i);
        float mm[24];
        #pragma unroll
        for (int i = 0; i < 6; ++i) {
            mm[4*i+0]=q[i].a[0]; mm[4*i+1]=q[i].a[1]; mm[4*i+2]=q[i].a[2]; mm[4*i+3]=q[i].a[3];
        }
        #pragma unroll
        for (int o = 0; o < 16; ++o)
            wout[o>>2].a[o&3] = K2*(mm[o+2]+mm[o+6]) + K1*(mm[o+3]+mm[o+5]) + K0*mm[o+4];
    }
    __syncthreads();

    // ---- phase C: write s1 overlay back into u
    if (has) {
        #pragma unroll
        for (int f = 0; f < 4; ++f) *UF4(jch, jr, 4*jh + f) = wout[f].v;
    }
    __syncthreads();

    // ---- phase D: H-conv from overlay + store
    size_t base = (size_t)d*HW + (h0+ty)*W_ + w0 + 4*tx;
    #pragma unroll
    for (int ch = 0; ch < 3; ++ch) {
        F4 q0, q1, q2, q3, q4;
        q0.v = *UF4(ch, ty  , tx);
        q1.v = *UF4(ch, ty+1, tx);
        q2.v = *UF4(ch, ty+2, tx);
        q3.v = *UF4(ch, ty+3, tx);
        q4.v = *UF4(ch, ty+4, tx);
        float4 s2;
        s2.x = K2*(q0.a[0]+q4.a[0]) + K1*(q1.a[0]+q3.a[0]) + K0*q2.a[0];
        s2.y = K2*(q0.a[1]+q4.a[1]) + K1*(q1.a[1]+q3.a[1]) + K0*q2.a[1];
        s2.z = K2*(q0.a[2]+q4.a[2]) + K1*(q1.a[2]+q3.a[2]) + K0*q2.a[2];
        s2.w = K2*(q0.a[3]+q4.a[3]) + K1*(q1.a[3]+q3.a[3]) + K0*q2.a[3];
        *(float4*)(tout + (size_t)ch*NVOX + base) = s2;
    }
    #undef UF4
}

// ---------------------------------------------------------------------------
// v8 smooth_d_warp (UNCHANGED from the 554.7 µs run): v6 structure with
// staging via async global_load_lds width=16. Lean scalar trilerp + max TLP
// (v5/v7 proved the gather is line/latency-bound).
// ---------------------------------------------------------------------------
__global__ __launch_bounds__(256) void smooth_d_warp_kernel(const float* __restrict__ t,
                                                            const float* __restrict__ mov,
                                                            float* __restrict__ vf_out,
                                                            float* __restrict__ warped_out,
                                                            int do_warp) {
    __shared__ float4 sm[24][64];     // [ch*8 + r][hw4-lane], planes d0-2 .. d0+5
    const int chunk = (blockIdx.x & 7)*400 + (blockIdx.x >> 3);
    const int db = chunk / 100;       // d-tile: planes db*4 .. db*4+3
    const int hb = chunk % 100;       // hw-tile: f4 indices hb*64 .. hb*64+63
    const int tdx = threadIdx.x & 63; // hw4 lane
    const int tdz = threadIdx.x >> 6; // d lane 0..3 (== wave id)
    const int d0 = db*4;
    const int hw4 = hb*64 + tdx;

    // ---- stage 8 planes x 3 ch: 24 plane-rows, wave w stages rows w*6..w*6+5
    #pragma unroll
    for (int i = 0; i < 6; ++i) {
        int pc = tdz*6 + i;           // 0..23
        int ch = pc >> 3;             // pc/8
        int r  = pc & 7;              // plane row
        int p  = d0 - 2 + r;
        if ((unsigned)p < (unsigned)D_) {   // wave-uniform branch
            const float4* src = (const float4*)(t + (size_t)ch*NVOX) + (p*HW4 + hw4);
            GLOAD_LDS16(src, &sm[pc][tdx]);
        } else {
            sm[pc][tdx] = zero4();
        }
    }
    __syncthreads();

    // ---- D-conv from LDS + warp. Output (d0+tdz, hw4): taps rows tdz..tdz+4.
    const int d = d0 + tdz;
    const int w = (hw4 % (W_/4)) * 4;
    const int h = hw4 / (W_/4);
    F4 va[3];
    #pragma unroll
    for (int ch = 0; ch < 3; ++ch) {
        F4 q0, q1, q2, q3, q4;
        q0.v = sm[ch*8 + tdz    ][tdx];
        q1.v = sm[ch*8 + tdz + 1][tdx];
        q2.v = sm[ch*8 + tdz + 2][tdx];
        q3.v = sm[ch*8 + tdz + 3][tdx];
        q4.v = sm[ch*8 + tdz + 4][tdx];
        va[ch].a[0] = K2*(q0.a[0]+q4.a[0]) + K1*(q1.a[0]+q3.a[0]) + K0*q2.a[0];
        va[ch].a[1] = K2*(q0.a[1]+q4.a[1]) + K1*(q1.a[1]+q3.a[1]) + K0*q2.a[1];
        va[ch].a[2] = K2*(q0.a[2]+q4.a[2]) + K1*(q1.a[2]+q3.a[2]) + K0*q2.a[2];
        va[ch].a[3] = K2*(q0.a[3]+q4.a[3]) + K1*(q1.a[3]+q3.a[3]) + K0*q2.a[3];
    }
    const int i4 = d*HW4 + hw4;
    ((float4*)vf_out)[i4]        = va[0].v;
    ((float4*)vf_out)[i4 + N4]   = va[1].v;
    ((float4*)vf_out)[i4 + 2*N4] = va[2].v;
    if (do_warp) {
        F4 r4o;
        #pragma unroll
        for (int j = 0; j < 4; ++j) {
            float cd  = (float)d       + va[0].a[j];
            float ch2 = (float)h       + va[1].a[j];
            float cw  = (float)(w + j) + va[2].a[j];
            r4o.a[j] = trilerp(mov, cd, ch2, cw);
        }
        ((float4*)warped_out)[i4] = r4o.v;
    }
}

extern "C" void kernel_launch(void* const* d_in, const int* in_sizes, int n_in,
                              void* d_out, int out_size, void* d_ws, size_t ws_size,
                              hipStream_t stream) {
    const float* mov = (const float*)d_in[0];
    const float* fix = (const float*)d_in[1];
    const int ITERS = 10;

    float* ws     = (float*)d_ws;
    float* vfA    = ws;                       // 3N — the vf state
    float* tbuf   = ws + (size_t)3*NVOX;      // 3N — WH-smoothed field
    float* warped = ws + (size_t)6*NVOX;      // N

    for (int it = 0; it < ITERS; ++it) {
        // it==0: vf == 0 => warped == mov exactly (integer-coordinate trilerp)
        const float* wsrc = (it == 0) ? mov : warped;
        force_wh_kernel<<<dim3(3200), dim3(8,32), 0, stream>>>(wsrc, fix, vfA, tbuf,
                                                               it == 0 ? 1 : 0);
        float* vdst = (it == ITERS-1) ? (float*)d_out : vfA;
        smooth_d_warp_kernel<<<dim3(3200), dim3(256), 0, stream>>>(tbuf, mov, vdst, warped,
                                                                   it == ITERS-1 ? 0 : 1);
    }
}

// Round 10
// 535.664 us; speedup vs baseline: 1.1494x; 1.0052x over previous
//
#include <hip/hip_runtime.h>
#include <math.h>

#define D_ 128
#define H_ 160
#define W_ 160
#define NVOX (D_*H_*W_)
#define HW (H_*W_)
#define N4 (NVOX/4)
#define HW4 (HW/4)

// Gaussian kernel, sigma=1, radius=2, normalized
#define K0 0.40261996f
#define K1 0.24420134f
#define K2 0.05448868f

union F4 { float4 v; float a[4]; };

__device__ __forceinline__ float4 zero4() { float4 z; z.x=z.y=z.z=z.w=0.f; return z; }
__device__ __forceinline__ float4 bcast4(float x) { float4 r; r.x=r.y=r.z=r.w=x; return r; }

// async global->LDS, 16B per lane. HW semantics: LDS dest = wave-uniform base
// + lane*16 (our base+lane patterns match exactly); global src is per-lane.
#define GLOAD_LDS16(g, l) __builtin_amdgcn_global_load_lds( \
    (const __attribute__((address_space(1))) void*)(g), \
    (__attribute__((address_space(3))) void*)(l), 16, 0, 0)

__device__ __forceinline__ float fetch_mov(const float* __restrict__ m, int d, int h, int w) {
    if ((unsigned)d >= (unsigned)D_ || (unsigned)h >= (unsigned)H_ || (unsigned)w >= (unsigned)W_) return 0.0f;
    return m[(size_t)(d*H_ + h)*W_ + w];
}

__device__ __forceinline__ float trilerp(const float* __restrict__ mov,
                                         float cd, float ch, float cw) {
    float fd = floorf(cd), fh = floorf(ch), fw = floorf(cw);
    int di = (int)fd, hi = (int)fh, wi = (int)fw;
    float td = cd - fd, th = ch - fh, tw = cw - fw;
    float c000, c001, c010, c011, c100, c101, c110, c111;
    if (di >= 0 && di < D_-1 && hi >= 0 && hi < H_-1 && wi >= 0 && wi < W_-1) {
        const float* p = mov + (size_t)di*HW + hi*W_ + wi;
        c000 = p[0];    c001 = p[1];
        c010 = p[W_];   c011 = p[W_+1];
        const float* q = p + HW;
        c100 = q[0];    c101 = q[1];
        c110 = q[W_];   c111 = q[W_+1];
    } else {
        c000 = fetch_mov(mov, di,   hi,   wi  );
        c001 = fetch_mov(mov, di,   hi,   wi+1);
        c010 = fetch_mov(mov, di,   hi+1, wi  );
        c011 = fetch_mov(mov, di,   hi+1, wi+1);
        c100 = fetch_mov(mov, di+1, hi,   wi  );
        c101 = fetch_mov(mov, di+1, hi,   wi+1);
        c110 = fetch_mov(mov, di+1, hi+1, wi  );
        c111 = fetch_mov(mov, di+1, hi+1, wi+1);
    }
    float c00 = c000 + tw*(c001 - c000);
    float c01 = c010 + tw*(c011 - c010);
    float c10 = c100 + tw*(c101 - c100);
    float c11 = c110 + tw*(c111 - c110);
    float c0 = c00 + th*(c01 - c00);
    float c1 = c10 + th*(c11 - c10);
    return c0 + td*(c1 - c0);
}

// ---------------------------------------------------------------------------
// prep: S = mov + fix, DIFF = mov - fix (iteration 0's warped == mov exactly).
// ---------------------------------------------------------------------------
__global__ __launch_bounds__(256) void prep_kernel(const float* __restrict__ mov,
                                                   const float* __restrict__ fix,
                                                   float* __restrict__ S,
                                                   float* __restrict__ DIF) {
    int i4 = blockIdx.x*256 + threadIdx.x;
    if (i4 >= N4) return;
    F4 m4; m4.v = ((const float4*)mov)[i4];
    F4 f4; f4.v = ((const float4*)fix)[i4];
    F4 s4, d4;
    #pragma unroll
    for (int j = 0; j < 4; ++j) { s4.a[j] = m4.a[j] + f4.a[j]; d4.a[j] = m4.a[j] - f4.a[j]; }
    ((float4*)S)[i4]   = s4.v;
    ((float4*)DIF)[i4] = d4.v;
}

// ---------------------------------------------------------------------------
// v10 force_wh: demons force rewritten on SUM/DIFF volumes. Every gradient
// term is a warped+fix sum: G = s*(S_next - S_prev); only diff = warped-fix
// appears separately. smooth_d produces S/DIFF (it holds warped in regs).
//   A0: stage ONE S-tile [38][48] via gload_lds (456 slots, was 912).
//   A1: 6 coalesced b128/slot (2 S d-taps + 1 DIFF center + 3 vf, was 7) and
//       half the LDS tap reads. Edge rules unchanged: clamp-fill == center
//       substitution; d-edge offset 0 gives G0 = S_du - S_c == one-sided.
//   LDS 35.3 -> 28 KB: 5 blocks/CU. B/C/D byte-identical to v4..v9.
// FP note: only change is sum order inside G (a(x-y)+a(u-v) ->
// a((x+u)-(y+v)), ~1 ulp); the sole discontinuity (denom>1e-6 guard) needs
// 4 values <1e-3 simultaneously (P~1e-12/voxel) -- safe.
// ---------------------------------------------------------------------------
#define UROW 48   // 12 f4 per row (10 used + swizzle domain padding)

__global__ __launch_bounds__(256, 5) void force_wh_kernel(const float* __restrict__ S,
                                                          const float* __restrict__ DIF,
                                                          const float* __restrict__ vf,
                                                          float* __restrict__ tout,
                                                          int zero_vf) {
    __shared__ float u[3][36][UROW];  // phase A1 out; phase C/D: s1 overlay
    __shared__ float ts[38][48];      // S-tile, rows h0-3..h0+34, cols w0-8..w0+39 (clamped)
    const int tx = threadIdx.x;       // 0..7
    const int ty = threadIdx.y;       // 0..31
    const int tid = ty*8 + tx;
    const int bswz = (blockIdx.x & 7)*400 + (blockIdx.x >> 3);
    const int d   = bswz / 25;
    const int rem = bswz % 25;
    const int h0 = (rem / 5) * 32;
    const int w0 = (rem % 5) * 32;

    // swizzled f4 accessor: logical f4-col fc of row r lives at fc ^ (r&3)
    #define UF4(ch, r, fc) (((float4*)&u[(ch)][(r)][0]) + ((fc) ^ ((r)&3)))

    // ---- phase A0: stage S center-plane tile via gload_lds (h-clamp in src).
    {
        const float* splane = S + (size_t)d*HW;
        #pragma unroll
        for (int k = 0; k < 2; ++k) {
            int s = (k == 0) ? tid : 200 + tid;   // 0..255, 200..455: full waves
            int R  = s / 12, C4 = s % 12;
            int gh = h0 - 3 + R;
            int ghc = gh < 0 ? 0 : (gh > H_-1 ? H_-1 : gh);
            int gw = w0 - 8 + 4*C4;
            int gwc = gw < 0 ? 0 : (gw > W_-4 ? W_-4 : gw);
            GLOAD_LDS16(splane + (size_t)ghc*W_ + gwc, ((float4*)ts) + s);
        }
    }
    __syncthreads();
    if (w0 == 0 || w0 == 128) {       // wave-uniform: patch w-edge f4-cols with bcast edge value
        if (tid < 76) {
            int R = tid / 2, C = tid % 2;
            int dstc = (w0 == 0) ? C : (10 + C);     // f4-cols {0,1} or {10,11}
            int srcf = (w0 == 0) ? 8 : 39;           // float at gw=0 / gw=W-1
            float v = ts[R][srcf];
            *(float4*)&ts[R][4*dstc] = bcast4(v);
        }
        __syncthreads();
    }

    // ---- phase A1: demons force from S-tile taps + 6 batched global loads.
    for (int slot = tid; slot < 360; slot += 256) {
        int r = slot/10, c = slot%10;
        int gh = h0 - 2 + r;
        int gw = w0 - 4 + 4*c;
        F4 o0, o1, o2;
        if ((unsigned)gh < (unsigned)H_ && gw >= 0 && gw + 4 <= W_) {
            size_t base = (size_t)d*HW + (size_t)gh*W_ + gw;
            int i4 = (int)(base >> 2);
            int up = (d < D_-1) ?  (HW/4) : 0;   // clamped-plane offset == substitute rule
            int dn = (d > 0)    ? -(HW/4) : 0;
            const float4* S4 = (const float4*)S;
            F4 sdu, sdn, dff;
            sdu.v = S4[i4 + up];
            sdn.v = S4[i4 + dn];
            dff.v = ((const float4*)DIF)[i4];
            if (zero_vf) {
                o0.v = zero4(); o1.v = zero4(); o2.v = zero4();
            } else {
                o0.v = ((const float4*)vf)[i4];
                o1.v = ((const float4*)vf)[i4 + N4];
                o2.v = ((const float4*)vf)[i4 + 2*N4];
            }
            int sr = r + 1, sc = 4*c + 4;
            F4 scc, shu, shd;
            scc.v = *(const float4*)&ts[sr  ][sc];
            shu.v = *(const float4*)&ts[sr+1][sc];
            shd.v = *(const float4*)&ts[sr-1][sc];
            float sl = ts[sr][sc-1], sr2 = ts[sr][sc+4];
            float hs  = (gh==0 || gh==H_-1) ? 1.f : 0.5f;
            float dsc = (d==0  || d==D_-1)  ? 1.f : 0.5f;
            float m[6] = {sl, scc.a[0], scc.a[1], scc.a[2], scc.a[3], sr2};
            #pragma unroll
            for (int j = 0; j < 4; ++j) {
                int wj = gw + j;
                float wsc  = (wj == 0 || wj == W_-1) ? 1.f : 0.5f;
                float prev = (wj == 0)    ? m[1] : m[j];
                float next = (wj == W_-1) ? m[4] : m[j+2];
                float G0 = dsc*(sdu.a[j] - sdn.a[j]);
                float G1 = hs *(shu.a[j] - shd.a[j]);
                float G2 = wsc*(next - prev);
                float diff = dff.a[j];
                float denom = G0*G0 + G1*G1 + G2*G2 + diff*diff;
                float scale = (denom > 1e-6f) ? (-diff/denom) : 0.0f;
                o0.a[j] += scale*G0;
                o1.a[j] += scale*G1;
                o2.a[j] += scale*G2;
            }
        } else {
            o0.v = zero4(); o1.v = zero4(); o2.v = zero4();
        }
        *UF4(0, r, c) = o0.v;
        *UF4(1, r, c) = o1.v;
        *UF4(2, r, c) = o2.v;
    }
    __syncthreads();

    // ---- phase B: W-conv into registers. 216 jobs = 3ch x 36 rows x 2 halves.
    F4 wout[4];
    int jch = 0, jr = 0, jh = 0;
    const bool has = (tid < 216);
    if (has) {
        jch = tid / 72;
        int rem2 = tid % 72;
        jr = rem2 >> 1;
        jh = rem2 & 1;
        F4 q[6];
        #pragma unroll
        for (int i = 0; i < 6; ++i) q[i].v = *UF4(jch, jr, 4*jh + i);
        float mm[24];
        #pragma unroll
        for (int i = 0; i < 6; ++i) {
            mm[4*i+0]=q[i].a[0]; mm[4*i+1]=q[i].a[1]; mm[4*i+2]=q[i].a[2]; mm[4*i+3]=q[i].a[3];
        }
        #pragma unroll
        for (int o = 0; o < 16; ++o)
            wout[o>>2].a[o&3] = K2*(mm[o+2]+mm[o+6]) + K1*(mm[o+3]+mm[o+5]) + K0*mm[o+4];
    }
    __syncthreads();

    // ---- phase C: write s1 overlay back into u
    if (has) {
        #pragma unroll
        for (int f = 0; f < 4; ++f) *UF4(jch, jr, 4*jh + f) = wout[f].v;
    }
    __syncthreads();

    // ---- phase D: H-conv from overlay + store
    size_t base = (size_t)d*HW + (h0+ty)*W_ + w0 + 4*tx;
    #pragma unroll
    for (int ch = 0; ch < 3; ++ch) {
        F4 q0, q1, q2, q3, q4;
        q0.v = *UF4(ch, ty  , tx);
        q1.v = *UF4(ch, ty+1, tx);
        q2.v = *UF4(ch, ty+2, tx);
        q3.v = *UF4(ch, ty+3, tx);
        q4.v = *UF4(ch, ty+4, tx);
        float4 s2;
        s2.x = K2*(q0.a[0]+q4.a[0]) + K1*(q1.a[0]+q3.a[0]) + K0*q2.a[0];
        s2.y = K2*(q0.a[1]+q4.a[1]) + K1*(q1.a[1]+q3.a[1]) + K0*q2.a[1];
        s2.z = K2*(q0.a[2]+q4.a[2]) + K1*(q1.a[2]+q3.a[2]) + K0*q2.a[2];
        s2.w = K2*(q0.a[3]+q4.a[3]) + K1*(q1.a[3]+q3.a[3]) + K0*q2.a[3];
        *(float4*)(tout + (size_t)ch*NVOX + base) = s2;
    }
    #undef UF4
}

// ---------------------------------------------------------------------------
// v10 smooth_d_warp: v8 structure (async gload_lds staging, lean scalar
// trilerp, max TLP) + S/DIFF production: one coalesced fix read, warped
// (in regs) combined to S = w+f, DIFF = w-f; two stores replace the warped
// store. Last iteration (do_warp=0) skips all of it.
// ---------------------------------------------------------------------------
__global__ __launch_bounds__(256) void smooth_d_warp_kernel(const float* __restrict__ t,
                                                            const float* __restrict__ mov,
                                                            const float* __restrict__ fix,
                                                            float* __restrict__ vf_out,
                                                            float* __restrict__ S_out,
                                                            float* __restrict__ D_out,
                                                            int do_warp) {
    __shared__ float4 sm[24][64];     // [ch*8 + r][hw4-lane], planes d0-2 .. d0+5
    const int chunk = (blockIdx.x & 7)*400 + (blockIdx.x >> 3);
    const int db = chunk / 100;       // d-tile: planes db*4 .. db*4+3
    const int hb = chunk % 100;       // hw-tile: f4 indices hb*64 .. hb*64+63
    const int tdx = threadIdx.x & 63; // hw4 lane
    const int tdz = threadIdx.x >> 6; // d lane 0..3 (== wave id)
    const int d0 = db*4;
    const int hw4 = hb*64 + tdx;

    // ---- stage 8 planes x 3 ch: 24 plane-rows, wave w stages rows w*6..w*6+5
    #pragma unroll
    for (int i = 0; i < 6; ++i) {
        int pc = tdz*6 + i;           // 0..23
        int ch = pc >> 3;             // pc/8
        int r  = pc & 7;              // plane row
        int p  = d0 - 2 + r;
        if ((unsigned)p < (unsigned)D_) {   // wave-uniform branch
            const float4* src = (const float4*)(t + (size_t)ch*NVOX) + (p*HW4 + hw4);
            GLOAD_LDS16(src, &sm[pc][tdx]);
        } else {
            sm[pc][tdx] = zero4();
        }
    }
    __syncthreads();

    // ---- D-conv from LDS + warp. Output (d0+tdz, hw4): taps rows tdz..tdz+4.
    const int d = d0 + tdz;
    const int w = (hw4 % (W_/4)) * 4;
    const int h = hw4 / (W_/4);
    F4 va[3];
    #pragma unroll
    for (int ch = 0; ch < 3; ++ch) {
        F4 q0, q1, q2, q3, q4;
        q0.v = sm[ch*8 + tdz    ][tdx];
        q1.v = sm[ch*8 + tdz + 1][tdx];
        q2.v = sm[ch*8 + tdz + 2][tdx];
        q3.v = sm[ch*8 + tdz + 3][tdx];
        q4.v = sm[ch*8 + tdz + 4][tdx];
        va[ch].a[0] = K2*(q0.a[0]+q4.a[0]) + K1*(q1.a[0]+q3.a[0]) + K0*q2.a[0];
        va[ch].a[1] = K2*(q0.a[1]+q4.a[1]) + K1*(q1.a[1]+q3.a[1]) + K0*q2.a[1];
        va[ch].a[2] = K2*(q0.a[2]+q4.a[2]) + K1*(q1.a[2]+q3.a[2]) + K0*q2.a[2];
        va[ch].a[3] = K2*(q0.a[3]+q4.a[3]) + K1*(q1.a[3]+q3.a[3]) + K0*q2.a[3];
    }
    const int i4 = d*HW4 + hw4;
    ((float4*)vf_out)[i4]        = va[0].v;
    ((float4*)vf_out)[i4 + N4]   = va[1].v;
    ((float4*)vf_out)[i4 + 2*N4] = va[2].v;
    if (do_warp) {
        F4 r4o;
        #pragma unroll
        for (int j = 0; j < 4; ++j) {
            float cd  = (float)d       + va[0].a[j];
            float ch2 = (float)h       + va[1].a[j];
            float cw  = (float)(w + j) + va[2].a[j];
            r4o.a[j] = trilerp(mov, cd, ch2, cw);
        }
        F4 fx; fx.v = ((const float4*)fix)[i4];
        F4 s4o, d4o;
        #pragma unroll
        for (int j = 0; j < 4; ++j) {
            s4o.a[j] = r4o.a[j] + fx.a[j];
            d4o.a[j] = r4o.a[j] - fx.a[j];
        }
        ((float4*)S_out)[i4] = s4o.v;
        ((float4*)D_out)[i4] = d4o.v;
    }
}

extern "C" void kernel_launch(void* const* d_in, const int* in_sizes, int n_in,
                              void* d_out, int out_size, void* d_ws, size_t ws_size,
                              hipStream_t stream) {
    const float* mov = (const float*)d_in[0];
    const float* fix = (const float*)d_in[1];
    const int ITERS = 10;

    float* ws     = (float*)d_ws;
    float* vfA    = ws;                       // 3N — the vf state
    float* tbuf   = ws + (size_t)3*NVOX;      // 3N — WH-smoothed field
    float* Svol   = ws + (size_t)6*NVOX;      // N  — warped + fix
    float* Dvol   = ws + (size_t)7*NVOX;      // N  — warped - fix

    prep_kernel<<<dim3(3200), dim3(256), 0, stream>>>(mov, fix, Svol, Dvol);

    for (int it = 0; it < ITERS; ++it) {
        force_wh_kernel<<<dim3(3200), dim3(8,32), 0, stream>>>(Svol, Dvol, vfA, tbuf,
                                                               it == 0 ? 1 : 0);
        float* vdst = (it == ITERS-1) ? (float*)d_out : vfA;
        smooth_d_warp_kernel<<<dim3(3200), dim3(256), 0, stream>>>(tbuf, mov, fix, vdst,
                                                                   Svol, Dvol,
                                                                   it == ITERS-1 ? 0 : 1);
    }
}